// Round 1
// baseline (6775.344 us; speedup 1.0000x reference)
//
#include <hip/hip_runtime.h>
#include <hip/hip_bf16.h>

// GRU: SEQ=64, BATCH=64, HID=EMB=512, VOCAB=10000, LAYERS=2
// Outputs: logits (64,64,10000) f32 then h_final (2,64,512) f32, concat flat.

#define SEQ 64
#define NB_GRU 24   // persistent-GRU grid (<= #CUs, all co-resident)

typedef short s16x8 __attribute__((ext_vector_type(8)));   // 8 bf16 (4 VGPRs)
typedef float f32x4 __attribute__((ext_vector_type(4)));

static __device__ __forceinline__ unsigned short f2bf(float f){
    unsigned int u = __float_as_uint(f);
    return (unsigned short)((u + 0x7FFFu + ((u >> 16) & 1u)) >> 16);  // RNE
}
static __device__ __forceinline__ float bf2f(unsigned short s){
    return __uint_as_float(((unsigned int)s) << 16);
}
static __device__ __forceinline__ float sigm(float x){ return 1.0f / (1.0f + __expf(-x)); }

// ---------------------------------------------------------------- prep ------
// Builds: emb_bf (4096x512 bf16 gather), WxT0 (1536x512), UhT0 (1024x512),
// UhtT0 (512x512), B3T (1536x1024 = [Wx1 ; Uh1|0] transposed), UhtT1,
// decpad (10112x512, zero-padded rows), HH/HHbf init, barrier reset.
__global__ void prep_kernel(const int* __restrict__ inputs, const float* __restrict__ hidden,
    const float* __restrict__ emb, const float* __restrict__ Wx, const float* __restrict__ Uh,
    const float* __restrict__ Uht, const float* __restrict__ dec_w,
    unsigned short* __restrict__ emb_bf, unsigned short* __restrict__ WxT0,
    unsigned short* __restrict__ UhT0, unsigned short* __restrict__ UhtT0,
    unsigned short* __restrict__ B3T, unsigned short* __restrict__ UhtT1,
    unsigned short* __restrict__ decpad,
    float* __restrict__ HH, unsigned short* __restrict__ HHbf, unsigned int* __restrict__ bar)
{
    const long long stride = (long long)gridDim.x * blockDim.x;
    const long long t0 = (long long)blockIdx.x * blockDim.x + threadIdx.x;
    for (long long i = t0; i < 4096LL*512; i += stride){
        int r = (int)(i >> 9), k = (int)(i & 511);
        emb_bf[i] = f2bf(emb[(long long)inputs[r]*512 + k]);
    }
    for (long long i = t0; i < 1536LL*512; i += stride){
        int n = (int)(i >> 9), k = (int)(i & 511);
        WxT0[i] = f2bf(Wx[(long long)k*1536 + n]);
    }
    for (long long i = t0; i < 1024LL*512; i += stride){
        int n = (int)(i >> 9), k = (int)(i & 511);
        UhT0[i] = f2bf(Uh[(long long)k*1024 + n]);
    }
    for (long long i = t0; i < 512LL*512; i += stride){
        int n = (int)(i >> 9), k = (int)(i & 511);
        UhtT0[i] = f2bf(Uht[(long long)k*512 + n]);
    }
    for (long long i = t0; i < 1536LL*1024; i += stride){
        int n = (int)(i >> 10), k2 = (int)(i & 1023);
        float v;
        if (k2 < 512) v = Wx[(long long)(512 + k2)*1536 + n];          // Wx[1][k2][n]
        else { int k = k2 - 512; v = (n < 1024) ? Uh[(long long)(512 + k)*1024 + n] : 0.0f; }
        B3T[i] = f2bf(v);
    }
    for (long long i = t0; i < 512LL*512; i += stride){
        int n = (int)(i >> 9), k = (int)(i & 511);
        UhtT1[i] = f2bf(Uht[(long long)(512 + k)*512 + n]);
    }
    for (long long i = t0; i < 10112LL*512; i += stride){
        int n = (int)(i >> 9), k = (int)(i & 511);
        decpad[i] = (n < 10000) ? f2bf(dec_w[(long long)n*512 + k]) : (unsigned short)0;
    }
    for (long long i = t0; i < 65536; i += stride){
        int b = (int)(i >> 10), c = (int)(i & 1023);
        int l = c >> 9, j = c & 511;
        float v = hidden[((long long)l*64 + b)*512 + j];
        HH[i] = v; HHbf[i] = f2bf(v);                                  // HH[b][l*512+j]
    }
    if (t0 == 0) *bar = 0u;
}

// ------------------------------------------------- tiled 128x128 bf16 GEMM --
// A (MxK row-major bf16), BT (NxK row-major bf16), K%32==0, M%128==0, N%128==0.
// mode 0: outB[row*N+col] = bf16(acc)        (WX0 precompute)
// mode 1: if col<Nreal: outF[row*Nreal+col] = acc + bias[col]   (decoder)
__global__ __launch_bounds__(256) void gemm128(const unsigned short* __restrict__ A,
    const unsigned short* __restrict__ BT, int M, int N, int K, int mode,
    float* __restrict__ outF, unsigned short* __restrict__ outB,
    const float* __restrict__ bias, int Nreal)
{
    __shared__ unsigned short Ash[128*32];
    __shared__ unsigned short Bsh[128*32];
    const int nT = N >> 7;
    const int mb = blockIdx.x / nT, nb = blockIdx.x % nT;
    const int tid = threadIdx.x;
    const int lane = tid & 63, wId = tid >> 6;
    const int wm = wId >> 1, wn = wId & 1;
    const int ln = lane & 15, kg = lane >> 4;
    f32x4 acc[4][4];
    #pragma unroll
    for (int mt = 0; mt < 4; ++mt)
        #pragma unroll
        for (int nt = 0; nt < 4; ++nt) acc[mt][nt] = f32x4{0.f,0.f,0.f,0.f};

    for (int kc = 0; kc < K; kc += 32){
        #pragma unroll
        for (int it = 0; it < 2; ++it){
            int flat = it*256 + tid;
            int row = flat >> 2, kq = flat & 3;
            *(int4*)(&Ash[flat*8]) = *(const int4*)(A + (long long)(mb*128 + row)*K + kc + kq*8);
            *(int4*)(&Bsh[flat*8]) = *(const int4*)(BT + (long long)(nb*128 + row)*K + kc + kq*8);
        }
        __syncthreads();
        s16x8 af[4], bfv[4];
        #pragma unroll
        for (int mt = 0; mt < 4; ++mt) af[mt]  = *(const s16x8*)(&Ash[(wm*64 + mt*16 + ln)*32 + kg*8]);
        #pragma unroll
        for (int nt = 0; nt < 4; ++nt) bfv[nt] = *(const s16x8*)(&Bsh[(wn*64 + nt*16 + ln)*32 + kg*8]);
        #pragma unroll
        for (int mt = 0; mt < 4; ++mt)
            #pragma unroll
            for (int nt = 0; nt < 4; ++nt)
                acc[mt][nt] = __builtin_amdgcn_mfma_f32_16x16x32_bf16(af[mt], bfv[nt], acc[mt][nt], 0, 0, 0);
        __syncthreads();
    }
    #pragma unroll
    for (int mt = 0; mt < 4; ++mt)
        #pragma unroll
        for (int nt = 0; nt < 4; ++nt)
            #pragma unroll
            for (int r = 0; r < 4; ++r){
                int row = mb*128 + wm*64 + mt*16 + kg*4 + r;   // C/D: col=lane&15, row=(lane>>4)*4+reg
                int col = nb*128 + wn*64 + nt*16 + ln;
                float v = acc[mt][nt][r];
                if (mode == 0){
                    outB[(long long)row*N + col] = f2bf(v);
                } else {
                    if (col < Nreal) outF[(long long)row*Nreal + col] = v + bias[col];
                }
            }
}

// -------------------------------------------------------- persistent GRU ----
static __device__ __forceinline__ void gsync(unsigned int* bar, unsigned int target){
    __syncthreads();
    if (threadIdx.x == 0){
        __threadfence();                     // release: drain our writes to L2
        atomicAdd(bar, 1u);
        while (__hip_atomic_load(bar, __ATOMIC_RELAXED, __HIP_MEMORY_SCOPE_AGENT) < target){ }
        __threadfence();                     // acquire: invalidate L1 for fresh reads
    }
    __syncthreads();
}

// One wave computes a 64x16 C-tile (4 M-frags), fragments straight from L2 (no LDS).
static __device__ __forceinline__ void mm64(const unsigned short* __restrict__ A, int strideA,
    const unsigned short* __restrict__ BT, int K, int n0, int ln, int kg, f32x4 acc[4])
{
    #pragma unroll
    for (int mt = 0; mt < 4; ++mt) acc[mt] = f32x4{0.f,0.f,0.f,0.f};
    for (int kc = 0; kc < K; kc += 32){
        s16x8 bv = *(const s16x8*)(BT + (long long)(n0 + ln)*K + kc + kg*8);
        #pragma unroll
        for (int mt = 0; mt < 4; ++mt){
            s16x8 av = *(const s16x8*)(A + (long long)(mt*16 + ln)*strideA + kc + kg*8);
            acc[mt] = __builtin_amdgcn_mfma_f32_16x16x32_bf16(av, bv, acc[mt], 0, 0, 0);
        }
    }
}

__global__ __launch_bounds__(256) void gru_kernel(
    float* __restrict__ HH, unsigned short* __restrict__ HHbf,
    const unsigned short* __restrict__ UhT0, const unsigned short* __restrict__ UhtT0,
    const unsigned short* __restrict__ B3T,  const unsigned short* __restrict__ UhtT1,
    const unsigned short* __restrict__ WX0,
    unsigned short* __restrict__ rh0, unsigned short* __restrict__ rh1,
    float* __restrict__ z0, float* __restrict__ z1, float* __restrict__ P3,
    unsigned short* __restrict__ H2bf, const float* __restrict__ b_rzh,
    float* __restrict__ outTail, unsigned int* __restrict__ bar)
{
    const int tid = threadIdx.x;
    const int lane = tid & 63, wv = tid >> 6;
    const int ln = lane & 15, kg = lane >> 4;
    const int nb = blockIdx.x;
    const int NB = gridDim.x;
    unsigned int gen = 0;
    const float* b0 = b_rzh;
    const float* b1 = b_rzh + 1536;
    f32x4 acc[4];

    for (int t = 0; t < SEQ; ++t){
        const long long wxrow = (long long)t * 64;
        // ---- S1: uh = h0 @ Uh0 (N=1024); rh0 = sig(wx_r+uh_r+b)*h0 ; z0 = sig(...)
        if (nb < 16){
            int n0 = nb*64 + wv*16;
            mm64(HHbf, 1024, UhT0, 512, n0, ln, kg, acc);
            int n = n0 + ln;
            #pragma unroll
            for (int mt = 0; mt < 4; ++mt)
                #pragma unroll
                for (int r = 0; r < 4; ++r){
                    int b = mt*16 + kg*4 + r;
                    float pre = acc[mt][r] + bf2f(WX0[(wxrow + b)*1536 + n]) + b0[n];
                    float s = sigm(pre);
                    if (n < 512) rh0[b*512 + n] = f2bf(s * HH[b*1024 + n]);
                    else         z0[b*512 + (n - 512)] = s;
                }
        }
        gen += NB; gsync(bar, gen);
        // ---- S2: ht = tanh(wx_h + rh0@Uht0 + b) ; h0 <- (1-z)h0 + z*ht
        if (nb < 8){
            int n0 = nb*64 + wv*16;
            mm64(rh0, 512, UhtT0, 512, n0, ln, kg, acc);
            int n = n0 + ln;
            #pragma unroll
            for (int mt = 0; mt < 4; ++mt)
                #pragma unroll
                for (int r = 0; r < 4; ++r){
                    int b = mt*16 + kg*4 + r;
                    float pre = acc[mt][r] + bf2f(WX0[(wxrow + b)*1536 + 1024 + n]) + b0[1024 + n];
                    float ht = tanhf(pre);
                    float z = z0[b*512 + n];
                    float hp = HH[b*1024 + n];
                    float hn = (1.0f - z)*hp + z*ht;
                    HH[b*1024 + n] = hn;
                    HHbf[b*1024 + n] = f2bf(hn);
                }
        }
        gen += NB; gsync(bar, gen);
        // ---- S3: [h0|h1] @ B3T (N=1536): n<512 -> rh1, n<1024 -> z1, else P3=wx_h(L1)
        if (nb < 24){
            int n0 = nb*64 + wv*16;
            mm64(HHbf, 1024, B3T, 1024, n0, ln, kg, acc);
            int n = n0 + ln;
            #pragma unroll
            for (int mt = 0; mt < 4; ++mt)
                #pragma unroll
                for (int r = 0; r < 4; ++r){
                    int b = mt*16 + kg*4 + r;
                    float v = acc[mt][r];
                    if (n < 512){
                        float s = sigm(v + b1[n]);
                        rh1[b*512 + n] = f2bf(s * HH[b*1024 + 512 + n]);
                    } else if (n < 1024){
                        z1[b*512 + (n - 512)] = sigm(v + b1[n]);
                    } else {
                        P3[b*512 + (n - 1024)] = v;
                    }
                }
        }
        gen += NB; gsync(bar, gen);
        // ---- S4: ht = tanh(P3 + rh1@Uht1 + b) ; h1 <- (1-z)h1 + z*ht ; H2bf[t]
        if (nb < 8){
            int n0 = nb*64 + wv*16;
            mm64(rh1, 512, UhtT1, 512, n0, ln, kg, acc);
            int n = n0 + ln;
            #pragma unroll
            for (int mt = 0; mt < 4; ++mt)
                #pragma unroll
                for (int r = 0; r < 4; ++r){
                    int b = mt*16 + kg*4 + r;
                    float pre = acc[mt][r] + P3[b*512 + n] + b1[1024 + n];
                    float ht = tanhf(pre);
                    float z = z1[b*512 + n];
                    float hp = HH[b*1024 + 512 + n];
                    float hn = (1.0f - z)*hp + z*ht;
                    HH[b*1024 + 512 + n] = hn;
                    HHbf[b*1024 + 512 + n] = f2bf(hn);
                    H2bf[(wxrow + b)*512 + n] = f2bf(hn);
                }
        }
        gen += NB; gsync(bar, gen);
    }
    // h_final tail: out[(l*64+b)*512 + j] = HH[b*1024 + l*512 + j]
    for (int i = nb*256 + tid; i < 65536; i += NB*256){
        int b = i >> 10, c = i & 1023, l = c >> 9, j = c & 511;
        outTail[l*32768 + b*512 + j] = HH[i];
    }
}

// ---------------------------------------------------------------- launch ----
extern "C" void kernel_launch(void* const* d_in, const int* in_sizes, int n_in,
                              void* d_out, int out_size, void* d_ws, size_t ws_size,
                              hipStream_t stream)
{
    const int*   inputs = (const int*)d_in[0];
    const float* hidden = (const float*)d_in[1];
    const float* emb    = (const float*)d_in[2];
    const float* Wx     = (const float*)d_in[3];
    const float* Uh     = (const float*)d_in[4];
    const float* Uht    = (const float*)d_in[5];
    const float* b_rzh  = (const float*)d_in[6];
    const float* dec_w  = (const float*)d_in[7];
    const float* dec_b  = (const float*)d_in[8];
    float* out = (float*)d_out;

    char* w = (char*)d_ws;
    size_t off = 0;
    auto alloc = [&](size_t bytes)->char*{
        char* p = w + off; off = (off + bytes + 255) & ~(size_t)255; return p;
    };
    unsigned short* emb_bf = (unsigned short*)alloc(4096LL*512*2);
    unsigned short* WxT0   = (unsigned short*)alloc(1536LL*512*2);
    unsigned short* WX0    = (unsigned short*)alloc(4096LL*1536*2);
    unsigned short* UhT0   = (unsigned short*)alloc(1024LL*512*2);
    unsigned short* UhtT0  = (unsigned short*)alloc(512LL*512*2);
    unsigned short* B3T    = (unsigned short*)alloc(1536LL*1024*2);
    unsigned short* UhtT1  = (unsigned short*)alloc(512LL*512*2);
    unsigned short* decpad = (unsigned short*)alloc(10112LL*512*2);
    float*          HH     = (float*)alloc(65536*4);
    unsigned short* HHbf   = (unsigned short*)alloc(65536*2);
    unsigned short* rh0    = (unsigned short*)alloc(64*512*2);
    unsigned short* rh1    = (unsigned short*)alloc(64*512*2);
    float*          z0     = (float*)alloc(64*512*4);
    float*          z1     = (float*)alloc(64*512*4);
    float*          P3     = (float*)alloc(64*512*4);
    unsigned short* H2bf   = (unsigned short*)alloc(4096LL*512*2);
    unsigned int*   bar    = (unsigned int*)alloc(256);
    if (off > ws_size) return;  // workspace too small: fail loudly via absmax

    prep_kernel<<<1024, 256, 0, stream>>>(inputs, hidden, emb, Wx, Uh, Uht, dec_w,
        emb_bf, WxT0, UhT0, UhtT0, B3T, UhtT1, decpad, HH, HHbf, bar);

    // WX0 = embed @ Wx0  (M=4096, N=1536, K=512), bf16 out
    gemm128<<<dim3(32*12), 256, 0, stream>>>(emb_bf, WxT0, 4096, 1536, 512,
        0, nullptr, WX0, nullptr, 1536);

    // persistent recurrent kernel (24 co-resident blocks, manual grid barrier)
    gru_kernel<<<dim3(NB_GRU), 256, 0, stream>>>(HH, HHbf, UhT0, UhtT0, B3T, UhtT1,
        WX0, rh0, rh1, z0, z1, P3, H2bf, b_rzh, out + 40960000, bar);

    // decoder: logits = H2 @ dec_w^T + dec_b  (M=4096, N=10112 padded, K=512)
    gemm128<<<dim3(32*79), 256, 0, stream>>>(H2bf, decpad, 4096, 10112, 512,
        1, out, nullptr, dec_b, 10000);
}

// Round 2
// 5417.509 us; speedup vs baseline: 1.2506x; 1.2506x over previous
//
#include <hip/hip_runtime.h>
#include <hip/hip_bf16.h>

// GRU: SEQ=64, BATCH=64, HID=EMB=512, VOCAB=10000, LAYERS=2
// Outputs: logits (64,64,10000) f32 then h_final (2,64,512) f32, concat flat.

#define SEQ 64
#define NBG 20   // persistent-GRU grid: 20 blocks x 512 threads = 160 waves

typedef short s16x8 __attribute__((ext_vector_type(8)));   // 8 bf16 (4 VGPRs)
typedef float f32x4 __attribute__((ext_vector_type(4)));
typedef unsigned long long ull;

static __device__ __forceinline__ unsigned short f2bf(float f){
    unsigned int u = __float_as_uint(f);
    return (unsigned short)((u + 0x7FFFu + ((u >> 16) & 1u)) >> 16);  // RNE
}
static __device__ __forceinline__ float bf2f(unsigned short s){
    return __uint_as_float(((unsigned int)s) << 16);
}
static __device__ __forceinline__ float sigm(float x){
    return __fdividef(1.0f, 1.0f + __expf(-x));
}
static __device__ __forceinline__ float tanh_fast(float x){
    float ax = fabsf(x);
    float e = __expf(-2.0f * ax);
    float r = __fdividef(1.0f - e, 1.0f + e);
    return copysignf(r, x);
}

// ---- coherent (agent-scope, cache-bypassing) access helpers ----------------
static __device__ __forceinline__ ull cload(const ull* p){
    return __hip_atomic_load(p, __ATOMIC_RELAXED, __HIP_MEMORY_SCOPE_AGENT);
}
static __device__ __forceinline__ void cstore(ull* p, ull v){
    __hip_atomic_store(p, v, __ATOMIC_RELAXED, __HIP_MEMORY_SCOPE_AGENT);
}
static __device__ __forceinline__ float cloadf(const float* p){
    return __hip_atomic_load(p, __ATOMIC_RELAXED, __HIP_MEMORY_SCOPE_AGENT);
}
static __device__ __forceinline__ void cload4f(const float* p, float out[4]){
    union { ull u; float f[2]; } a, b;
    a.u = cload((const ull*)p);
    b.u = cload((const ull*)(p + 2));
    out[0]=a.f[0]; out[1]=a.f[1]; out[2]=b.f[0]; out[3]=b.f[1];
}
static __device__ __forceinline__ void cstore4f(float* p, const float v[4]){
    union { ull u; float f[2]; } a, b;
    a.f[0]=v[0]; a.f[1]=v[1]; b.f[0]=v[2]; b.f[1]=v[3];
    cstore((ull*)p, a.u);
    cstore((ull*)(p + 2), b.u);
}
static __device__ __forceinline__ ull pack4bf(const float v[4]){
    union { ull u; unsigned short s[4]; } x;
    x.s[0]=f2bf(v[0]); x.s[1]=f2bf(v[1]); x.s[2]=f2bf(v[2]); x.s[3]=f2bf(v[3]);
    return x.u;
}

// ---------------------------------------------------------------- prep ------
__global__ void prep_kernel(const int* __restrict__ inputs, const float* __restrict__ hidden,
    const float* __restrict__ emb, const float* __restrict__ Wx, const float* __restrict__ Uh,
    const float* __restrict__ Uht, const float* __restrict__ dec_w,
    unsigned short* __restrict__ emb_bf, unsigned short* __restrict__ WxT0,
    unsigned short* __restrict__ UhT0, unsigned short* __restrict__ UhtT0,
    unsigned short* __restrict__ B3T, unsigned short* __restrict__ UhtT1,
    unsigned short* __restrict__ decpad,
    float* __restrict__ HH, unsigned short* __restrict__ HHbf, unsigned int* __restrict__ bar)
{
    const long long stride = (long long)gridDim.x * blockDim.x;
    const long long t0 = (long long)blockIdx.x * blockDim.x + threadIdx.x;
    for (long long i = t0; i < 4096LL*512; i += stride){
        int r = (int)(i >> 9), k = (int)(i & 511);
        emb_bf[i] = f2bf(emb[(long long)inputs[r]*512 + k]);
    }
    for (long long i = t0; i < 1536LL*512; i += stride){
        int n = (int)(i >> 9), k = (int)(i & 511);
        WxT0[i] = f2bf(Wx[(long long)k*1536 + n]);
    }
    for (long long i = t0; i < 1024LL*512; i += stride){
        int n = (int)(i >> 9), k = (int)(i & 511);
        UhT0[i] = f2bf(Uh[(long long)k*1024 + n]);
    }
    for (long long i = t0; i < 512LL*512; i += stride){
        int n = (int)(i >> 9), k = (int)(i & 511);
        UhtT0[i] = f2bf(Uht[(long long)k*512 + n]);
    }
    for (long long i = t0; i < 1536LL*1024; i += stride){
        int n = (int)(i >> 10), k2 = (int)(i & 1023);
        float v;
        if (k2 < 512) v = Wx[(long long)(512 + k2)*1536 + n];          // Wx[1][k2][n]
        else { int k = k2 - 512; v = (n < 1024) ? Uh[(long long)(512 + k)*1024 + n] : 0.0f; }
        B3T[i] = f2bf(v);
    }
    for (long long i = t0; i < 512LL*512; i += stride){
        int n = (int)(i >> 9), k = (int)(i & 511);
        UhtT1[i] = f2bf(Uht[(long long)(512 + k)*512 + n]);
    }
    for (long long i = t0; i < 10112LL*512; i += stride){
        int n = (int)(i >> 9), k = (int)(i & 511);
        decpad[i] = (n < 10000) ? f2bf(dec_w[(long long)n*512 + k]) : (unsigned short)0;
    }
    for (long long i = t0; i < 65536; i += stride){
        int b = (int)(i >> 10), c = (int)(i & 1023);
        int l = c >> 9, j = c & 511;
        float v = hidden[((long long)l*64 + b)*512 + j];
        HH[i] = v; HHbf[i] = f2bf(v);                                  // HH[b][l*512+j]
    }
    if (t0 == 0) *bar = 0u;
}

// ------------------------------------------------- tiled 128x128 bf16 GEMM --
__global__ __launch_bounds__(256) void gemm128(const unsigned short* __restrict__ A,
    const unsigned short* __restrict__ BT, int M, int N, int K, int mode,
    float* __restrict__ outF, unsigned short* __restrict__ outB,
    const float* __restrict__ bias, int Nreal)
{
    __shared__ unsigned short Ash[128*32];
    __shared__ unsigned short Bsh[128*32];
    const int nT = N >> 7;
    const int mb = blockIdx.x / nT, nb = blockIdx.x % nT;
    const int tid = threadIdx.x;
    const int lane = tid & 63, wId = tid >> 6;
    const int wm = wId >> 1, wn = wId & 1;
    const int ln = lane & 15, kg = lane >> 4;
    f32x4 acc[4][4];
    #pragma unroll
    for (int mt = 0; mt < 4; ++mt)
        #pragma unroll
        for (int nt = 0; nt < 4; ++nt) acc[mt][nt] = f32x4{0.f,0.f,0.f,0.f};

    for (int kc = 0; kc < K; kc += 32){
        #pragma unroll
        for (int it = 0; it < 2; ++it){
            int flat = it*256 + tid;
            int row = flat >> 2, kq = flat & 3;
            *(int4*)(&Ash[flat*8]) = *(const int4*)(A + (long long)(mb*128 + row)*K + kc + kq*8);
            *(int4*)(&Bsh[flat*8]) = *(const int4*)(BT + (long long)(nb*128 + row)*K + kc + kq*8);
        }
        __syncthreads();
        s16x8 af[4], bfv[4];
        #pragma unroll
        for (int mt = 0; mt < 4; ++mt) af[mt]  = *(const s16x8*)(&Ash[(wm*64 + mt*16 + ln)*32 + kg*8]);
        #pragma unroll
        for (int nt = 0; nt < 4; ++nt) bfv[nt] = *(const s16x8*)(&Bsh[(wn*64 + nt*16 + ln)*32 + kg*8]);
        #pragma unroll
        for (int mt = 0; mt < 4; ++mt)
            #pragma unroll
            for (int nt = 0; nt < 4; ++nt)
                acc[mt][nt] = __builtin_amdgcn_mfma_f32_16x16x32_bf16(af[mt], bfv[nt], acc[mt][nt], 0, 0, 0);
        __syncthreads();
    }
    #pragma unroll
    for (int mt = 0; mt < 4; ++mt)
        #pragma unroll
        for (int nt = 0; nt < 4; ++nt)
            #pragma unroll
            for (int r = 0; r < 4; ++r){
                int row = mb*128 + wm*64 + mt*16 + kg*4 + r;   // C/D: col=lane&15, row=(lane>>4)*4+reg
                int col = nb*128 + wn*64 + nt*16 + ln;
                float v = acc[mt][nt][r];
                if (mode == 0){
                    outB[(long long)row*N + col] = f2bf(v);
                } else {
                    if (col < Nreal) outF[(long long)row*Nreal + col] = v + bias[col];
                }
            }
}

// -------------------------------------------------------- persistent GRU ----
// Lightweight barrier: all data moves through agent-coherent atomics, so no
// cache-flushing fences are needed. __syncthreads() drains vmcnt(0) before
// s_barrier (HIP semantics), so every block's coherent stores are globally
// visible before its arrival increment.
static __device__ __forceinline__ void gsync(unsigned int* bar, unsigned int target){
    __syncthreads();
    if (threadIdx.x == 0){
        __hip_atomic_fetch_add(bar, 1u, __ATOMIC_RELAXED, __HIP_MEMORY_SCOPE_AGENT);
        while (__hip_atomic_load(bar, __ATOMIC_RELAXED, __HIP_MEMORY_SCOPE_AGENT) < target){ }
    }
    __syncthreads();
}

// Transposed wave-tile GEMM: D[64 n-rows][16 b-cols].
// A-side (4 fragments, mt over n): weights W (N,K) row-major, normal cached loads.
// B-side (1 fragment): one h-row (b = b0+ln), coherent 8B loads.
// C/D layout: col(b)=lane&15, row(n)=(lane>>4)*4+reg.
template<int KIT>
static __device__ __forceinline__ void mm64T(const unsigned short* __restrict__ W,
    const ull* __restrict__ Hrow, int ln, int kg, f32x4 acc[4])
{
    constexpr int K = KIT * 32;
    #pragma unroll
    for (int mt = 0; mt < 4; ++mt) acc[mt] = f32x4{0.f,0.f,0.f,0.f};
    #pragma unroll 2
    for (int k = 0; k < KIT; ++k){
        const int ko = k*32 + kg*8;
        union { ull u[2]; s16x8 v; } bfr;
        bfr.u[0] = cload(Hrow + (ko >> 2));
        bfr.u[1] = cload(Hrow + (ko >> 2) + 1);
        #pragma unroll
        for (int mt = 0; mt < 4; ++mt){
            s16x8 av = *(const s16x8*)(W + (mt*16 + ln)*K + ko);
            acc[mt] = __builtin_amdgcn_mfma_f32_16x16x32_bf16(av, bfr.v, acc[mt], 0, 0, 0);
        }
    }
}

__global__ __launch_bounds__(512, 4) void gru_kernel(
    float* __restrict__ HHf, unsigned short* __restrict__ HHbf,
    const unsigned short* __restrict__ UhT0, const unsigned short* __restrict__ UhtT0,
    const unsigned short* __restrict__ B3T,  const unsigned short* __restrict__ UhtT1,
    const unsigned short* __restrict__ WX0,
    unsigned short* __restrict__ rh0, unsigned short* __restrict__ rh1,
    float* __restrict__ z0, float* __restrict__ z1, float* __restrict__ P3,
    unsigned short* __restrict__ H2bf, const float* __restrict__ b_rzh,
    float* __restrict__ outTail, unsigned int* __restrict__ bar)
{
    const int tid  = threadIdx.x;
    const int lane = tid & 63;
    const int wv   = tid >> 6;                    // 0..7
    const int gw   = blockIdx.x * 8 + wv;         // 0..159
    const int ln   = lane & 15, kg = lane >> 4;
    const float* b0 = b_rzh;
    const float* b1 = b_rzh + 1536;
    const ull* Hu = (const ull*)HHbf;             // h rows: 1024 bf16 = 256 ull
    unsigned int gen = 0;
    f32x4 acc[4];

    for (int ss = 0; ss <= SEQ; ++ss){
        // =============== phase A: S1(ss) [L0 gates] || S3(ss-1) [L1 gates] ==
        if (gw < 64){
            if (ss < SEQ){
                const int ng = gw >> 2, bg = gw & 3;
                const int b = bg*16 + ln;
                mm64T<16>(UhT0 + ng*64*512, Hu + b*256, ln, kg, acc);
                const int t = ss;
                #pragma unroll
                for (int mt = 0; mt < 4; ++mt){
                    const int nq = ng*64 + mt*16 + kg*4;
                    union { ull u; unsigned short s[4]; } wx;
                    wx.u = *(const ull*)(WX0 + (long long)(t*64 + b)*1536 + nq);
                    float s[4];
                    #pragma unroll
                    for (int r = 0; r < 4; ++r)
                        s[r] = sigm(acc[mt][r] + bf2f(wx.s[r]) + b0[nq + r]);
                    if (nq < 512){
                        float h[4]; cload4f(HHf + b*1024 + nq, h);
                        float rv[4];
                        #pragma unroll
                        for (int r = 0; r < 4; ++r) rv[r] = s[r] * h[r];
                        cstore((ull*)(rh0 + b*512 + nq), pack4bf(rv));
                    } else {
                        cstore4f(z0 + b*512 + (nq - 512), s);
                    }
                }
            }
        } else {
            if (ss >= 1){
                const int j = gw - 64;                 // 0..95
                const int ng = j >> 2, bg = j & 3;
                const int b = bg*16 + ln;
                mm64T<32>(B3T + ng*64*1024, Hu + b*256, ln, kg, acc);
                #pragma unroll
                for (int mt = 0; mt < 4; ++mt){
                    const int nq = ng*64 + mt*16 + kg*4;   // [0,1536)
                    if (nq < 512){
                        float h[4]; cload4f(HHf + b*1024 + 512 + nq, h);
                        float rv[4];
                        #pragma unroll
                        for (int r = 0; r < 4; ++r)
                            rv[r] = sigm(acc[mt][r] + b1[nq + r]) * h[r];
                        cstore((ull*)(rh1 + b*512 + nq), pack4bf(rv));
                    } else if (nq < 1024){
                        float s[4];
                        #pragma unroll
                        for (int r = 0; r < 4; ++r)
                            s[r] = sigm(acc[mt][r] + b1[nq + r]);
                        cstore4f(z1 + b*512 + (nq - 512), s);
                    } else {
                        float v[4];
                        #pragma unroll
                        for (int r = 0; r < 4; ++r) v[r] = acc[mt][r];
                        cstore4f(P3 + b*512 + (nq - 1024), v);
                    }
                }
            }
        }
        gen += NBG; gsync(bar, gen);

        // =============== phase B: S2(ss) [h0 update] || S4(ss-1) [h1 update]
        if (gw < 32){
            if (ss < SEQ){
                const int ng = gw >> 2, bg = gw & 3;
                const int b = bg*16 + ln;
                mm64T<16>(UhtT0 + ng*64*512, (const ull*)rh0 + b*128, ln, kg, acc);
                const int t = ss;
                #pragma unroll
                for (int mt = 0; mt < 4; ++mt){
                    const int nq = ng*64 + mt*16 + kg*4;   // [0,512)
                    union { ull u; unsigned short s[4]; } wx;
                    wx.u = *(const ull*)(WX0 + (long long)(t*64 + b)*1536 + 1024 + nq);
                    float z[4], hp[4], hn[4];
                    cload4f(z0 + b*512 + nq, z);
                    cload4f(HHf + b*1024 + nq, hp);
                    #pragma unroll
                    for (int r = 0; r < 4; ++r){
                        float pre = acc[mt][r] + bf2f(wx.s[r]) + b0[1024 + nq + r];
                        float ht = tanh_fast(pre);
                        hn[r] = (1.0f - z[r])*hp[r] + z[r]*ht;
                    }
                    cstore4f(HHf + b*1024 + nq, hn);
                    cstore((ull*)(HHbf + b*1024 + nq), pack4bf(hn));
                }
            }
        } else if (gw < 64){
            if (ss >= 1){
                const int g = gw - 32;
                const int ng = g >> 2, bg = g & 3;
                const int b = bg*16 + ln;
                mm64T<16>(UhtT1 + ng*64*512, (const ull*)rh1 + b*128, ln, kg, acc);
                const int t = ss - 1;
                #pragma unroll
                for (int mt = 0; mt < 4; ++mt){
                    const int nq = ng*64 + mt*16 + kg*4;   // [0,512)
                    float p3[4], z[4], hp[4], hn[4];
                    cload4f(P3 + b*512 + nq, p3);
                    cload4f(z1 + b*512 + nq, z);
                    cload4f(HHf + b*1024 + 512 + nq, hp);
                    #pragma unroll
                    for (int r = 0; r < 4; ++r){
                        float pre = acc[mt][r] + p3[r] + b1[1024 + nq + r];
                        float ht = tanh_fast(pre);
                        hn[r] = (1.0f - z[r])*hp[r] + z[r]*ht;
                    }
                    cstore4f(HHf + b*1024 + 512 + nq, hn);
                    cstore((ull*)(HHbf + b*1024 + 512 + nq), pack4bf(hn));
                    *(ull*)(H2bf + (long long)(t*64 + b)*512 + nq) = pack4bf(hn);
                }
            }
        }
        gen += NBG; gsync(bar, gen);
    }

    // h_final tail: out[(l*64+b)*512 + j] = HHf[b*1024 + l*512 + j]
    for (int i = blockIdx.x*512 + tid; i < 65536; i += NBG*512){
        int b = i >> 10, c = i & 1023, l = c >> 9, j = c & 511;
        outTail[l*32768 + b*512 + j] = cloadf(HHf + i);
    }
}

// ---------------------------------------------------------------- launch ----
extern "C" void kernel_launch(void* const* d_in, const int* in_sizes, int n_in,
                              void* d_out, int out_size, void* d_ws, size_t ws_size,
                              hipStream_t stream)
{
    const int*   inputs = (const int*)d_in[0];
    const float* hidden = (const float*)d_in[1];
    const float* emb    = (const float*)d_in[2];
    const float* Wx     = (const float*)d_in[3];
    const float* Uh     = (const float*)d_in[4];
    const float* Uht    = (const float*)d_in[5];
    const float* b_rzh  = (const float*)d_in[6];
    const float* dec_w  = (const float*)d_in[7];
    const float* dec_b  = (const float*)d_in[8];
    float* out = (float*)d_out;

    char* w = (char*)d_ws;
    size_t off = 0;
    auto alloc = [&](size_t bytes)->char*{
        char* p = w + off; off = (off + bytes + 255) & ~(size_t)255; return p;
    };
    unsigned short* emb_bf = (unsigned short*)alloc(4096LL*512*2);
    unsigned short* WxT0   = (unsigned short*)alloc(1536LL*512*2);
    unsigned short* WX0    = (unsigned short*)alloc(4096LL*1536*2);
    unsigned short* UhT0   = (unsigned short*)alloc(1024LL*512*2);
    unsigned short* UhtT0  = (unsigned short*)alloc(512LL*512*2);
    unsigned short* B3T    = (unsigned short*)alloc(1536LL*1024*2);
    unsigned short* UhtT1  = (unsigned short*)alloc(512LL*512*2);
    unsigned short* decpad = (unsigned short*)alloc(10112LL*512*2);
    float*          HH     = (float*)alloc(65536*4);
    unsigned short* HHbf   = (unsigned short*)alloc(65536*2);
    unsigned short* rh0    = (unsigned short*)alloc(64*512*2);
    unsigned short* rh1    = (unsigned short*)alloc(64*512*2);
    float*          z0     = (float*)alloc(64*512*4);
    float*          z1     = (float*)alloc(64*512*4);
    float*          P3     = (float*)alloc(64*512*4);
    unsigned short* H2bf   = (unsigned short*)alloc(4096LL*512*2);
    unsigned int*   bar    = (unsigned int*)alloc(256);
    if (off > ws_size) return;  // workspace too small: fail loudly via absmax

    prep_kernel<<<1024, 256, 0, stream>>>(inputs, hidden, emb, Wx, Uh, Uht, dec_w,
        emb_bf, WxT0, UhT0, UhtT0, B3T, UhtT1, decpad, HH, HHbf, bar);

    // WX0 = embed @ Wx0  (M=4096, N=1536, K=512), bf16 out
    gemm128<<<dim3(32*12), 256, 0, stream>>>(emb_bf, WxT0, 4096, 1536, 512,
        0, nullptr, WX0, nullptr, 1536);

    // persistent recurrent kernel (20 co-resident blocks, coherent-atomic sync)
    gru_kernel<<<dim3(NBG), 512, 0, stream>>>(HH, HHbf, UhT0, UhtT0, B3T, UhtT1,
        WX0, rh0, rh1, z0, z1, P3, H2bf, b_rzh, out + 40960000, bar);

    // decoder: logits = H2 @ dec_w^T + dec_b  (M=4096, N=10112 padded, K=512)
    gemm128<<<dim3(32*79), 256, 0, stream>>>(H2bf, decpad, 4096, 10112, 512,
        1, out, nullptr, dec_b, 10000);
}

// Round 3
// 4847.396 us; speedup vs baseline: 1.3977x; 1.1176x over previous
//
#include <hip/hip_runtime.h>
#include <hip/hip_bf16.h>

// GRU: SEQ=64, BATCH=64, HID=EMB=512, VOCAB=10000, LAYERS=2
// Outputs: logits (64,64,10000) f32 then h_final (2,64,512) f32, concat flat.

#define SEQ 64
#define NBG 16   // persistent-GRU grid: 16 blocks x 512 threads

typedef short s16x8 __attribute__((ext_vector_type(8)));   // 8 bf16 (4 VGPRs)
typedef float f32x4 __attribute__((ext_vector_type(4)));
typedef unsigned long long ull;

static __device__ __forceinline__ unsigned short f2bf(float f){
    unsigned int u = __float_as_uint(f);
    return (unsigned short)((u + 0x7FFFu + ((u >> 16) & 1u)) >> 16);  // RNE
}
static __device__ __forceinline__ float bf2f(unsigned short s){
    return __uint_as_float(((unsigned int)s) << 16);
}
static __device__ __forceinline__ float sigm(float x){
    return __fdividef(1.0f, 1.0f + __expf(-x));
}
static __device__ __forceinline__ float tanh_fast(float x){
    float ax = fabsf(x);
    float e = __expf(-2.0f * ax);
    float r = __fdividef(1.0f - e, 1.0f + e);
    return copysignf(r, x);
}

// ---- coherent (agent-scope, cache-bypassing) access helpers ----------------
static __device__ __forceinline__ ull cload(const ull* p){
    return __hip_atomic_load(p, __ATOMIC_RELAXED, __HIP_MEMORY_SCOPE_AGENT);
}
static __device__ __forceinline__ void cstore(ull* p, ull v){
    __hip_atomic_store(p, v, __ATOMIC_RELAXED, __HIP_MEMORY_SCOPE_AGENT);
}
static __device__ __forceinline__ float cloadf(const float* p){
    return __hip_atomic_load(p, __ATOMIC_RELAXED, __HIP_MEMORY_SCOPE_AGENT);
}
static __device__ __forceinline__ void cstore4f(float* p, const float v[4]){
    union { ull u; float f[2]; } a, b;
    a.f[0]=v[0]; a.f[1]=v[1]; b.f[0]=v[2]; b.f[1]=v[3];
    cstore((ull*)p, a.u);
    cstore((ull*)(p + 2), b.u);
}
static __device__ __forceinline__ ull pack4bf(const float v[4]){
    union { ull u; unsigned short s[4]; } x;
    x.s[0]=f2bf(v[0]); x.s[1]=f2bf(v[1]); x.s[2]=f2bf(v[2]); x.s[3]=f2bf(v[3]);
    return x.u;
}

// ---------------------------------------------------------------- prep ------
__global__ void prep_kernel(const int* __restrict__ inputs, const float* __restrict__ hidden,
    const float* __restrict__ emb, const float* __restrict__ Wx, const float* __restrict__ Uh,
    const float* __restrict__ Uht, const float* __restrict__ dec_w,
    unsigned short* __restrict__ emb_bf, unsigned short* __restrict__ WxT0,
    unsigned short* __restrict__ UhT0, unsigned short* __restrict__ UhtT0,
    unsigned short* __restrict__ B3T, unsigned short* __restrict__ UhtT1,
    unsigned short* __restrict__ decpad,
    float* __restrict__ HH, unsigned short* __restrict__ HHbf, unsigned int* __restrict__ bar)
{
    const long long stride = (long long)gridDim.x * blockDim.x;
    const long long t0 = (long long)blockIdx.x * blockDim.x + threadIdx.x;
    for (long long i = t0; i < 4096LL*512; i += stride){
        int r = (int)(i >> 9), k = (int)(i & 511);
        emb_bf[i] = f2bf(emb[(long long)inputs[r]*512 + k]);
    }
    for (long long i = t0; i < 1536LL*512; i += stride){
        int n = (int)(i >> 9), k = (int)(i & 511);
        WxT0[i] = f2bf(Wx[(long long)k*1536 + n]);
    }
    for (long long i = t0; i < 1024LL*512; i += stride){
        int n = (int)(i >> 9), k = (int)(i & 511);
        UhT0[i] = f2bf(Uh[(long long)k*1024 + n]);
    }
    for (long long i = t0; i < 512LL*512; i += stride){
        int n = (int)(i >> 9), k = (int)(i & 511);
        UhtT0[i] = f2bf(Uht[(long long)k*512 + n]);
    }
    for (long long i = t0; i < 1536LL*1024; i += stride){
        int n = (int)(i >> 10), k2 = (int)(i & 1023);
        float v;
        if (k2 < 512) v = Wx[(long long)(512 + k2)*1536 + n];          // Wx[1][k2][n]
        else { int k = k2 - 512; v = (n < 1024) ? Uh[(long long)(512 + k)*1024 + n] : 0.0f; }
        B3T[i] = f2bf(v);
    }
    for (long long i = t0; i < 512LL*512; i += stride){
        int n = (int)(i >> 9), k = (int)(i & 511);
        UhtT1[i] = f2bf(Uht[(long long)(512 + k)*512 + n]);
    }
    for (long long i = t0; i < 10112LL*512; i += stride){
        int n = (int)(i >> 9), k = (int)(i & 511);
        decpad[i] = (n < 10000) ? f2bf(dec_w[(long long)n*512 + k]) : (unsigned short)0;
    }
    for (long long i = t0; i < 65536; i += stride){
        int b = (int)(i >> 10), c = (int)(i & 1023);
        int l = c >> 9, j = c & 511;
        float v = hidden[((long long)l*64 + b)*512 + j];
        HH[i] = v; HHbf[i] = f2bf(v);                                  // HH[b][l*512+j]
    }
    if (t0 == 0) *bar = 0u;
}

// ------------------------------------------------- tiled 128x128 bf16 GEMM --
__global__ __launch_bounds__(256) void gemm128(const unsigned short* __restrict__ A,
    const unsigned short* __restrict__ BT, int M, int N, int K, int mode,
    float* __restrict__ outF, unsigned short* __restrict__ outB,
    const float* __restrict__ bias, int Nreal)
{
    __shared__ unsigned short Ash[128*32];
    __shared__ unsigned short Bsh[128*32];
    const int nT = N >> 7;
    const int mb = blockIdx.x / nT, nb = blockIdx.x % nT;
    const int tid = threadIdx.x;
    const int lane = tid & 63, wId = tid >> 6;
    const int wm = wId >> 1, wn = wId & 1;
    const int ln = lane & 15, kg = lane >> 4;
    f32x4 acc[4][4];
    #pragma unroll
    for (int mt = 0; mt < 4; ++mt)
        #pragma unroll
        for (int nt = 0; nt < 4; ++nt) acc[mt][nt] = f32x4{0.f,0.f,0.f,0.f};

    for (int kc = 0; kc < K; kc += 32){
        #pragma unroll
        for (int it = 0; it < 2; ++it){
            int flat = it*256 + tid;
            int row = flat >> 2, kq = flat & 3;
            *(int4*)(&Ash[flat*8]) = *(const int4*)(A + (long long)(mb*128 + row)*K + kc + kq*8);
            *(int4*)(&Bsh[flat*8]) = *(const int4*)(BT + (long long)(nb*128 + row)*K + kc + kq*8);
        }
        __syncthreads();
        s16x8 af[4], bfv[4];
        #pragma unroll
        for (int mt = 0; mt < 4; ++mt) af[mt]  = *(const s16x8*)(&Ash[(wm*64 + mt*16 + ln)*32 + kg*8]);
        #pragma unroll
        for (int nt = 0; nt < 4; ++nt) bfv[nt] = *(const s16x8*)(&Bsh[(wn*64 + nt*16 + ln)*32 + kg*8]);
        #pragma unroll
        for (int mt = 0; mt < 4; ++mt)
            #pragma unroll
            for (int nt = 0; nt < 4; ++nt)
                acc[mt][nt] = __builtin_amdgcn_mfma_f32_16x16x32_bf16(af[mt], bfv[nt], acc[mt][nt], 0, 0, 0);
        __syncthreads();
    }
    #pragma unroll
    for (int mt = 0; mt < 4; ++mt)
        #pragma unroll
        for (int nt = 0; nt < 4; ++nt)
            #pragma unroll
            for (int r = 0; r < 4; ++r){
                int row = mb*128 + wm*64 + mt*16 + kg*4 + r;   // C/D: col=lane&15, row=(lane>>4)*4+reg
                int col = nb*128 + wn*64 + nt*16 + ln;
                float v = acc[mt][nt][r];
                if (mode == 0){
                    outB[(long long)row*N + col] = f2bf(v);
                } else {
                    if (col < Nreal) outF[(long long)row*Nreal + col] = v + bias[col];
                }
            }
}

// -------------------------------------------------------- persistent GRU ----
static __device__ __forceinline__ void gsync(unsigned int* bar, unsigned int target){
    __syncthreads();
    if (threadIdx.x == 0){
        __hip_atomic_fetch_add(bar, 1u, __ATOMIC_RELAXED, __HIP_MEMORY_SCOPE_AGENT);
        while (__hip_atomic_load(bar, __ATOMIC_RELAXED, __HIP_MEMORY_SCOPE_AGENT) < target)
            __builtin_amdgcn_s_sleep(1);
    }
    __syncthreads();
}

// Wave-tile GEMM: D[64 n][64 b], A = weights (N,K) from global (cached),
// B = 4 b-fragments from XOR-swizzled LDS. C/D: col(b)=lane&15, row(n)=(lane>>4)*4+reg.
template<int KIT, int PITCH>
static __device__ __forceinline__ void mmTile(const unsigned short* __restrict__ W,
    const char* __restrict__ lds, int ln, int kg, f32x4 acc[4][4])
{
    constexpr int K = KIT * 32;
    #pragma unroll
    for (int mt = 0; mt < 4; ++mt)
        #pragma unroll
        for (int nt = 0; nt < 4; ++nt) acc[mt][nt] = f32x4{0.f,0.f,0.f,0.f};
    #pragma unroll 2
    for (int k = 0; k < KIT; ++k){
        s16x8 bv[4];
        #pragma unroll
        for (int nt = 0; nt < 4; ++nt){
            const int row = nt*16 + ln;
            bv[nt] = *(const s16x8*)(lds + ((row*PITCH + k*64 + kg*16) ^ ((row & 7) << 4)));
        }
        #pragma unroll
        for (int mt = 0; mt < 4; ++mt){
            s16x8 av = *(const s16x8*)(W + (mt*16 + ln)*K + k*32 + kg*8);
            #pragma unroll
            for (int nt = 0; nt < 4; ++nt)
                acc[mt][nt] = __builtin_amdgcn_mfma_f32_16x16x32_bf16(av, bv[nt], acc[mt][nt], 0, 0, 0);
        }
    }
}

__global__ __launch_bounds__(512, 2) void gru_kernel(
    float* __restrict__ HHf, unsigned short* __restrict__ HHbf,
    const unsigned short* __restrict__ UhT0, const unsigned short* __restrict__ UhtT0,
    const unsigned short* __restrict__ B3T,  const unsigned short* __restrict__ UhtT1,
    const unsigned short* __restrict__ WX0,
    unsigned short* __restrict__ rh0, unsigned short* __restrict__ rh1,
    float* __restrict__ z0, float* __restrict__ z1, float* __restrict__ P3,
    unsigned short* __restrict__ H2bf, const float* __restrict__ b_rzh,
    float* __restrict__ outTail, unsigned int* __restrict__ bar)
{
    __shared__ __align__(16) char smem[131072];   // 128 KB
    const int tid = threadIdx.x, lane = tid & 63, wv = tid >> 6, blk = blockIdx.x;
    const int ln = lane & 15, kg = lane >> 4;
    const float* b0 = b_rzh;
    const float* b1 = b_rzh + 1536;
    const bool oddb = (blk & 1) != 0;
    const int ngB = blk >> 1;                     // phase-B tile (S2 even / S4 odd)
    unsigned int gen = 0;

    for (int ss = 0; ss <= SEQ; ++ss){
        // ===================== phase A: S1(ss) || S3(ss-1) ==================
        // stage H [64][1024] bf16 -> LDS (pitch 2048, byte ^= (row&7)<<4)
        {
            const ull* src = (const ull*)HHbf;
            for (int c = tid; c < 8192; c += 512){
                const int row = c >> 7, cb = c & 127;
                ull lo = cload(src + row*256 + cb*2);
                ull hi = cload(src + row*256 + cb*2 + 1);
                char* dst = smem + ((row*2048 + cb*16) ^ ((row & 7) << 4));
                *(ull*)dst = lo; *(ull*)(dst + 8) = hi;
            }
        }
        __syncthreads();
        if (wv == 0 && ss < SEQ){
            // ---- S1: uh = h0 @ Uh0, tile ng=blk over N=1024
            const int ng = blk;
            f32x4 acc[4][4];
            mmTile<16, 2048>(UhT0 + ng*64*512, smem, ln, kg, acc);
            const int t = ss;
            #pragma unroll
            for (int mt = 0; mt < 4; ++mt){
                const int nq = ng*64 + mt*16 + kg*4;
                #pragma unroll
                for (int nt = 0; nt < 4; ++nt){
                    const int b = nt*16 + ln;
                    union { ull u; unsigned short s[4]; } wx;
                    wx.u = *(const ull*)(WX0 + (long long)(t*64 + b)*1536 + nq);
                    float sg[4];
                    #pragma unroll
                    for (int r = 0; r < 4; ++r)
                        sg[r] = sigm(acc[mt][nt][r] + bf2f(wx.s[r]) + b0[nq + r]);
                    if (nq < 512){
                        union { ull u; unsigned short s[4]; } h;
                        h.u = *(const ull*)(smem + ((b*2048 + nq*2) ^ ((b & 7) << 4)));
                        float rv[4];
                        #pragma unroll
                        for (int r = 0; r < 4; ++r) rv[r] = sg[r] * bf2f(h.s[r]);
                        cstore((ull*)(rh0 + b*512 + nq), pack4bf(rv));
                    } else {
                        cstore4f(z0 + b*512 + (nq - 512), sg);
                    }
                }
            }
        } else if (ss >= 1 && (wv == 1 || (wv == 2 && !oddb))){
            // ---- S3: [h0|h1] @ B3T, 24 tiles over N=1536
            const int ng = (wv == 1) ? blk : 16 + (blk >> 1);
            f32x4 acc[4][4];
            mmTile<32, 2048>(B3T + ng*64*1024, smem, ln, kg, acc);
            #pragma unroll
            for (int mt = 0; mt < 4; ++mt){
                const int nq = ng*64 + mt*16 + kg*4;
                #pragma unroll
                for (int nt = 0; nt < 4; ++nt){
                    const int b = nt*16 + ln;
                    if (nq < 512){
                        union { ull u; unsigned short s[4]; } h;
                        h.u = *(const ull*)(smem + ((b*2048 + (512 + nq)*2) ^ ((b & 7) << 4)));
                        float rv[4];
                        #pragma unroll
                        for (int r = 0; r < 4; ++r)
                            rv[r] = sigm(acc[mt][nt][r] + b1[nq + r]) * bf2f(h.s[r]);
                        cstore((ull*)(rh1 + b*512 + nq), pack4bf(rv));
                    } else if (nq < 1024){
                        float sg[4];
                        #pragma unroll
                        for (int r = 0; r < 4; ++r)
                            sg[r] = sigm(acc[mt][nt][r] + b1[nq + r]);
                        cstore4f(z1 + b*512 + (nq - 512), sg);
                    } else {
                        float v[4];
                        #pragma unroll
                        for (int r = 0; r < 4; ++r) v[r] = acc[mt][nt][r];
                        cstore4f(P3 + b*512 + (nq - 1024), v);
                    }
                }
            }
        }
        gen += NBG; gsync(bar, gen);

        // ===================== phase B: S2(ss) || S4(ss-1) ==================
        // stage rh [64][512] bf16 (pitch 1024, swizzled) + f32 slices:
        //   Zb  @ 65536: z cols [ngB*64,+64)   (from z0/z1)
        //   Hp  @ 81920: h cols                (from HHf, +512 for odd)
        //   Pp  @ 98304: P3 cols               (odd blocks only)
        {
            const ull* srcR = (const ull*)(oddb ? rh1 : rh0);
            for (int c = tid; c < 4096; c += 512){
                const int row = c >> 6, cb = c & 63;
                ull lo = cload(srcR + row*128 + cb*2);
                ull hi = cload(srcR + row*128 + cb*2 + 1);
                char* dst = smem + ((row*1024 + cb*16) ^ ((row & 7) << 4));
                *(ull*)dst = lo; *(ull*)(dst + 8) = hi;
            }
            const float* srcZ = oddb ? z1 : z0;
            const float* srcH = HHf + (oddb ? 512 : 0);
            const int cb0 = ngB*64;
            for (int c = tid; c < 2048; c += 512){
                const int b = c >> 5, ch = c & 31;
                ull vz = cload((const ull*)(srcZ + b*512 + cb0) + ch);
                ull vh = cload((const ull*)(srcH + b*1024 + cb0) + ch);
                const int off = (ch*8) ^ ((b & 15) << 4);
                *(ull*)(smem + 65536 + b*256 + off) = vz;
                *(ull*)(smem + 81920 + b*256 + off) = vh;
            }
            if (oddb){
                for (int c = tid; c < 2048; c += 512){
                    const int b = c >> 5, ch = c & 31;
                    ull vp = cload((const ull*)(P3 + b*512 + cb0) + ch);
                    const int off = (ch*8) ^ ((b & 15) << 4);
                    *(ull*)(smem + 98304 + b*256 + off) = vp;
                }
            }
        }
        __syncthreads();
        if (wv == 0 && !oddb && ss < SEQ){
            // ---- S2: ht = tanh(wx_h + rh0@Uht0 + b); h0 update. tile ngB.
            f32x4 acc[4][4];
            mmTile<16, 1024>(UhtT0 + ngB*64*512, smem, ln, kg, acc);
            const int t = ss;
            #pragma unroll
            for (int mt = 0; mt < 4; ++mt){
                const int nq = ngB*64 + mt*16 + kg*4;   // < 512
                const int lc = mt*64 + kg*16;           // local col byte offset
                #pragma unroll
                for (int nt = 0; nt < 4; ++nt){
                    const int b = nt*16 + ln;
                    union { ull u; unsigned short s[4]; } wx;
                    wx.u = *(const ull*)(WX0 + (long long)(t*64 + b)*1536 + 1024 + nq);
                    const int off = lc ^ (ln << 4);
                    const float* zp = (const float*)(smem + 65536 + b*256 + off);
                    const float* hp = (const float*)(smem + 81920 + b*256 + off);
                    float hn[4];
                    #pragma unroll
                    for (int r = 0; r < 4; ++r){
                        float pre = acc[mt][nt][r] + bf2f(wx.s[r]) + b0[1024 + nq + r];
                        float ht = tanh_fast(pre);
                        float z = zp[r];
                        hn[r] = (1.0f - z)*hp[r] + z*ht;
                    }
                    cstore4f(HHf + b*1024 + nq, hn);
                    cstore((ull*)(HHbf + b*1024 + nq), pack4bf(hn));
                }
            }
        } else if (wv == 0 && oddb && ss >= 1){
            // ---- S4: ht = tanh(P3 + rh1@Uht1 + b); h1 update + H2bf. tile ngB.
            f32x4 acc[4][4];
            mmTile<16, 1024>(UhtT1 + ngB*64*512, smem, ln, kg, acc);
            const int t = ss - 1;
            #pragma unroll
            for (int mt = 0; mt < 4; ++mt){
                const int nq = ngB*64 + mt*16 + kg*4;   // < 512
                const int lc = mt*64 + kg*16;
                #pragma unroll
                for (int nt = 0; nt < 4; ++nt){
                    const int b = nt*16 + ln;
                    const int off = lc ^ (ln << 4);
                    const float* zp = (const float*)(smem + 65536 + b*256 + off);
                    const float* hp = (const float*)(smem + 81920 + b*256 + off);
                    const float* pp = (const float*)(smem + 98304 + b*256 + off);
                    float hn[4];
                    #pragma unroll
                    for (int r = 0; r < 4; ++r){
                        float pre = acc[mt][nt][r] + pp[r] + b1[1024 + nq + r];
                        float ht = tanh_fast(pre);
                        float z = zp[r];
                        hn[r] = (1.0f - z)*hp[r] + z*ht;
                    }
                    cstore4f(HHf + b*1024 + 512 + nq, hn);
                    cstore((ull*)(HHbf + b*1024 + 512 + nq), pack4bf(hn));
                    *(ull*)(H2bf + (long long)(t*64 + b)*512 + nq) = pack4bf(hn);
                }
            }
        }
        gen += NBG; gsync(bar, gen);
    }

    // h_final tail: out[(l*64+b)*512 + j] = HHf[b*1024 + l*512 + j]
    for (int i = blk*512 + tid; i < 65536; i += NBG*512){
        int b = i >> 10, c = i & 1023, l = c >> 9, j = c & 511;
        outTail[l*32768 + b*512 + j] = cloadf(HHf + i);
    }
}

// ---------------------------------------------------------------- launch ----
extern "C" void kernel_launch(void* const* d_in, const int* in_sizes, int n_in,
                              void* d_out, int out_size, void* d_ws, size_t ws_size,
                              hipStream_t stream)
{
    const int*   inputs = (const int*)d_in[0];
    const float* hidden = (const float*)d_in[1];
    const float* emb    = (const float*)d_in[2];
    const float* Wx     = (const float*)d_in[3];
    const float* Uh     = (const float*)d_in[4];
    const float* Uht    = (const float*)d_in[5];
    const float* b_rzh  = (const float*)d_in[6];
    const float* dec_w  = (const float*)d_in[7];
    const float* dec_b  = (const float*)d_in[8];
    float* out = (float*)d_out;

    char* w = (char*)d_ws;
    size_t off = 0;
    auto alloc = [&](size_t bytes)->char*{
        char* p = w + off; off = (off + bytes + 255) & ~(size_t)255; return p;
    };
    unsigned short* emb_bf = (unsigned short*)alloc(4096LL*512*2);
    unsigned short* WxT0   = (unsigned short*)alloc(1536LL*512*2);
    unsigned short* WX0    = (unsigned short*)alloc(4096LL*1536*2);
    unsigned short* UhT0   = (unsigned short*)alloc(1024LL*512*2);
    unsigned short* UhtT0  = (unsigned short*)alloc(512LL*512*2);
    unsigned short* B3T    = (unsigned short*)alloc(1536LL*1024*2);
    unsigned short* UhtT1  = (unsigned short*)alloc(512LL*512*2);
    unsigned short* decpad = (unsigned short*)alloc(10112LL*512*2);
    float*          HH     = (float*)alloc(65536*4);
    unsigned short* HHbf   = (unsigned short*)alloc(65536*2);
    unsigned short* rh0    = (unsigned short*)alloc(64*512*2);
    unsigned short* rh1    = (unsigned short*)alloc(64*512*2);
    float*          z0     = (float*)alloc(64*512*4);
    float*          z1     = (float*)alloc(64*512*4);
    float*          P3     = (float*)alloc(64*512*4);
    unsigned short* H2bf   = (unsigned short*)alloc(4096LL*512*2);
    unsigned int*   bar    = (unsigned int*)alloc(256);
    if (off > ws_size) return;  // workspace too small: fail loudly via absmax

    prep_kernel<<<1024, 256, 0, stream>>>(inputs, hidden, emb, Wx, Uh, Uht, dec_w,
        emb_bf, WxT0, UhT0, UhtT0, B3T, UhtT1, decpad, HH, HHbf, bar);

    // WX0 = embed @ Wx0  (M=4096, N=1536, K=512), bf16 out
    gemm128<<<dim3(32*12), 256, 0, stream>>>(emb_bf, WxT0, 4096, 1536, 512,
        0, nullptr, WX0, nullptr, 1536);

    // persistent recurrent kernel (16 co-resident blocks, LDS-staged phases)
    gru_kernel<<<dim3(NBG), 512, 0, stream>>>(HH, HHbf, UhT0, UhtT0, B3T, UhtT1,
        WX0, rh0, rh1, z0, z1, P3, H2bf, b_rzh, out + 40960000, bar);

    // decoder: logits = H2 @ dec_w^T + dec_b  (M=4096, N=10112 padded, K=512)
    gemm128<<<dim3(32*79), 256, 0, stream>>>(H2bf, decpad, 4096, 10112, 512,
        1, out, nullptr, dec_b, 10000);
}

// Round 4
// 4657.958 us; speedup vs baseline: 1.4546x; 1.0407x over previous
//
#include <hip/hip_runtime.h>
#include <hip/hip_bf16.h>

// GRU: SEQ=64, BATCH=64, HID=EMB=512, VOCAB=10000, LAYERS=2
// Outputs: logits (64,64,10000) f32 then h_final (2,64,512) f32, concat flat.

#define SEQ 64
#define NBG 16   // persistent-GRU grid: 16 blocks x 512 threads

typedef short s16x8 __attribute__((ext_vector_type(8)));   // 8 bf16 (4 VGPRs)
typedef float f32x4 __attribute__((ext_vector_type(4)));
typedef int   i32x4 __attribute__((ext_vector_type(4)));
typedef unsigned long long ull;

static __device__ __forceinline__ unsigned short f2bf(float f){
    unsigned int u = __float_as_uint(f);
    return (unsigned short)((u + 0x7FFFu + ((u >> 16) & 1u)) >> 16);  // RNE
}
static __device__ __forceinline__ float bf2f(unsigned short s){
    return __uint_as_float(((unsigned int)s) << 16);
}
static __device__ __forceinline__ float sigm(float x){
    return __fdividef(1.0f, 1.0f + __expf(-x));
}
static __device__ __forceinline__ float tanh_fast(float x){
    float ax = fabsf(x);
    float e = __expf(-2.0f * ax);
    float r = __fdividef(1.0f - e, 1.0f + e);
    return copysignf(r, x);
}

// ---- coherent (sc0 sc1 = bypass L1+L2, MALL-coherent) asm access ----------
// Loads: batch-issued, ONE waitcnt per batch (pipelined — the round-3 fix).
#define SC_LOAD8(OP,T0,T1,T2,T3,T4,T5,T6,T7,A0,A1,A2,A3,A4,A5,A6,A7)  \
  asm volatile(OP " %0, %8, off sc0 sc1\n\t"                           \
               OP " %1, %9, off sc0 sc1\n\t"                           \
               OP " %2, %10, off sc0 sc1\n\t"                          \
               OP " %3, %11, off sc0 sc1\n\t"                          \
               OP " %4, %12, off sc0 sc1\n\t"                          \
               OP " %5, %13, off sc0 sc1\n\t"                          \
               OP " %6, %14, off sc0 sc1\n\t"                          \
               OP " %7, %15, off sc0 sc1\n\t"                          \
               "s_waitcnt vmcnt(0)"                                    \
               : "=&v"(T0),"=&v"(T1),"=&v"(T2),"=&v"(T3),              \
                 "=&v"(T4),"=&v"(T5),"=&v"(T6),"=&v"(T7)               \
               : "v"(A0),"v"(A1),"v"(A2),"v"(A3),                      \
                 "v"(A4),"v"(A5),"v"(A6),"v"(A7)                       \
               : "memory")

#define SC_LOAD4(OP,T0,T1,T2,T3,A0,A1,A2,A3)                           \
  asm volatile(OP " %0, %4, off sc0 sc1\n\t"                           \
               OP " %1, %5, off sc0 sc1\n\t"                           \
               OP " %2, %6, off sc0 sc1\n\t"                           \
               OP " %3, %7, off sc0 sc1\n\t"                           \
               "s_waitcnt vmcnt(0)"                                    \
               : "=&v"(T0),"=&v"(T1),"=&v"(T2),"=&v"(T3)               \
               : "v"(A0),"v"(A1),"v"(A2),"v"(A3)                       \
               : "memory")

static __device__ __forceinline__ void sc_st8(void* p, ull v){
    asm volatile("global_store_dwordx2 %0, %1, off sc0 sc1" :: "v"(p), "v"(v) : "memory");
}
static __device__ __forceinline__ void sc_st16(void* p, f32x4 v){
    asm volatile("global_store_dwordx4 %0, %1, off sc0 sc1" :: "v"(p), "v"(v) : "memory");
}
static __device__ __forceinline__ f32x4 sc_ld16(const void* p){
    f32x4 v;
    asm volatile("global_load_dwordx4 %0, %1, off sc0 sc1\n\ts_waitcnt vmcnt(0)"
                 : "=v"(v) : "v"(p) : "memory");
    return v;
}
static __device__ __forceinline__ ull pack4bf(const float v[4]){
    union { ull u; unsigned short s[4]; } x;
    x.s[0]=f2bf(v[0]); x.s[1]=f2bf(v[1]); x.s[2]=f2bf(v[2]); x.s[3]=f2bf(v[3]);
    return x.u;
}

// ---------------------------------------------------------------- prep ------
__global__ void prep_kernel(const int* __restrict__ inputs, const float* __restrict__ hidden,
    const float* __restrict__ emb, const float* __restrict__ Wx, const float* __restrict__ Uh,
    const float* __restrict__ Uht, const float* __restrict__ dec_w,
    unsigned short* __restrict__ emb_bf, unsigned short* __restrict__ WxT0,
    unsigned short* __restrict__ UhT0, unsigned short* __restrict__ UhtT0,
    unsigned short* __restrict__ B3T, unsigned short* __restrict__ UhtT1,
    unsigned short* __restrict__ decpad,
    float* __restrict__ HH, unsigned short* __restrict__ HHbf, unsigned int* __restrict__ bar)
{
    const long long stride = (long long)gridDim.x * blockDim.x;
    const long long t0 = (long long)blockIdx.x * blockDim.x + threadIdx.x;
    for (long long i = t0; i < 4096LL*512; i += stride){
        int r = (int)(i >> 9), k = (int)(i & 511);
        emb_bf[i] = f2bf(emb[(long long)inputs[r]*512 + k]);
    }
    for (long long i = t0; i < 1536LL*512; i += stride){
        int n = (int)(i >> 9), k = (int)(i & 511);
        WxT0[i] = f2bf(Wx[(long long)k*1536 + n]);
    }
    for (long long i = t0; i < 1024LL*512; i += stride){
        int n = (int)(i >> 9), k = (int)(i & 511);
        UhT0[i] = f2bf(Uh[(long long)k*1024 + n]);
    }
    for (long long i = t0; i < 512LL*512; i += stride){
        int n = (int)(i >> 9), k = (int)(i & 511);
        UhtT0[i] = f2bf(Uht[(long long)k*512 + n]);
    }
    for (long long i = t0; i < 1536LL*1024; i += stride){
        int n = (int)(i >> 10), k2 = (int)(i & 1023);
        float v;
        if (k2 < 512) v = Wx[(long long)(512 + k2)*1536 + n];          // Wx[1][k2][n]
        else { int k = k2 - 512; v = (n < 1024) ? Uh[(long long)(512 + k)*1024 + n] : 0.0f; }
        B3T[i] = f2bf(v);
    }
    for (long long i = t0; i < 512LL*512; i += stride){
        int n = (int)(i >> 9), k = (int)(i & 511);
        UhtT1[i] = f2bf(Uht[(long long)(512 + k)*512 + n]);
    }
    for (long long i = t0; i < 10112LL*512; i += stride){
        int n = (int)(i >> 9), k = (int)(i & 511);
        decpad[i] = (n < 10000) ? f2bf(dec_w[(long long)n*512 + k]) : (unsigned short)0;
    }
    for (long long i = t0; i < 65536; i += stride){
        int b = (int)(i >> 10), c = (int)(i & 1023);
        int l = c >> 9, j = c & 511;
        float v = hidden[((long long)l*64 + b)*512 + j];
        HH[i] = v; HHbf[i] = f2bf(v);                                  // HH[b][l*512+j]
    }
    if (t0 == 0) *bar = 0u;
}

// ------------------------------------------------- tiled 128x128 bf16 GEMM --
__global__ __launch_bounds__(256) void gemm128(const unsigned short* __restrict__ A,
    const unsigned short* __restrict__ BT, int M, int N, int K, int mode,
    float* __restrict__ outF, unsigned short* __restrict__ outB,
    const float* __restrict__ bias, int Nreal)
{
    __shared__ unsigned short Ash[128*32];
    __shared__ unsigned short Bsh[128*32];
    const int nT = N >> 7;
    const int mb = blockIdx.x / nT, nb = blockIdx.x % nT;
    const int tid = threadIdx.x;
    const int lane = tid & 63, wId = tid >> 6;
    const int wm = wId >> 1, wn = wId & 1;
    const int ln = lane & 15, kg = lane >> 4;
    f32x4 acc[4][4];
    #pragma unroll
    for (int mt = 0; mt < 4; ++mt)
        #pragma unroll
        for (int nt = 0; nt < 4; ++nt) acc[mt][nt] = f32x4{0.f,0.f,0.f,0.f};

    for (int kc = 0; kc < K; kc += 32){
        #pragma unroll
        for (int it = 0; it < 2; ++it){
            int flat = it*256 + tid;
            int row = flat >> 2, kq = flat & 3;
            *(int4*)(&Ash[flat*8]) = *(const int4*)(A + (long long)(mb*128 + row)*K + kc + kq*8);
            *(int4*)(&Bsh[flat*8]) = *(const int4*)(BT + (long long)(nb*128 + row)*K + kc + kq*8);
        }
        __syncthreads();
        s16x8 af[4], bfv[4];
        #pragma unroll
        for (int mt = 0; mt < 4; ++mt) af[mt]  = *(const s16x8*)(&Ash[(wm*64 + mt*16 + ln)*32 + kg*8]);
        #pragma unroll
        for (int nt = 0; nt < 4; ++nt) bfv[nt] = *(const s16x8*)(&Bsh[(wn*64 + nt*16 + ln)*32 + kg*8]);
        #pragma unroll
        for (int mt = 0; mt < 4; ++mt)
            #pragma unroll
            for (int nt = 0; nt < 4; ++nt)
                acc[mt][nt] = __builtin_amdgcn_mfma_f32_16x16x32_bf16(af[mt], bfv[nt], acc[mt][nt], 0, 0, 0);
        __syncthreads();
    }
    #pragma unroll
    for (int mt = 0; mt < 4; ++mt)
        #pragma unroll
        for (int nt = 0; nt < 4; ++nt)
            #pragma unroll
            for (int r = 0; r < 4; ++r){
                int row = mb*128 + wm*64 + mt*16 + kg*4 + r;   // C/D: col=lane&15, row=(lane>>4)*4+reg
                int col = nb*128 + wn*64 + nt*16 + ln;
                float v = acc[mt][nt][r];
                if (mode == 0){
                    outB[(long long)row*N + col] = f2bf(v);
                } else {
                    if (col < Nreal) outF[(long long)row*Nreal + col] = v + bias[col];
                }
            }
}

// -------------------------------------------------------- persistent GRU ----
// All mutable cross-block data moves via sc0/sc1 asm ops (MALL-coherent,
// pipelined). Arrival = one atomicAdd per block; poll = tight sc-load loop.
static __device__ __forceinline__ void gsync(unsigned int* bar, unsigned int target){
    asm volatile("s_waitcnt vmcnt(0)" ::: "memory");   // drain this thread's sc-stores
    __syncthreads();
    if (threadIdx.x == 0){
        __hip_atomic_fetch_add(bar, 1u, __ATOMIC_RELAXED, __HIP_MEMORY_SCOPE_AGENT);
        unsigned int v;
        do {
            asm volatile("global_load_dword %0, %1, off sc0 sc1\n\ts_waitcnt vmcnt(0)"
                         : "=v"(v) : "v"(bar) : "memory");
        } while (v < target);
    }
    __syncthreads();
}

// Wave-tile GEMM: D[64 n][64 b], A = weights (N,K) from global (cached),
// B = 4 b-fragments from XOR-swizzled LDS. C/D: col(b)=lane&15, row(n)=(lane>>4)*4+reg.
template<int KIT, int PITCH>
static __device__ __forceinline__ void mmTile(const unsigned short* __restrict__ W,
    const char* __restrict__ lds, int ln, int kg, f32x4 acc[4][4])
{
    constexpr int K = KIT * 32;
    #pragma unroll
    for (int mt = 0; mt < 4; ++mt)
        #pragma unroll
        for (int nt = 0; nt < 4; ++nt) acc[mt][nt] = f32x4{0.f,0.f,0.f,0.f};
    #pragma unroll 2
    for (int k = 0; k < KIT; ++k){
        s16x8 bv[4];
        #pragma unroll
        for (int nt = 0; nt < 4; ++nt){
            const int row = nt*16 + ln;
            bv[nt] = *(const s16x8*)(lds + ((row*PITCH + k*64 + kg*16) ^ ((row & 7) << 4)));
        }
        #pragma unroll
        for (int mt = 0; mt < 4; ++mt){
            s16x8 av = *(const s16x8*)(W + (mt*16 + ln)*K + k*32 + kg*8);
            #pragma unroll
            for (int nt = 0; nt < 4; ++nt)
                acc[mt][nt] = __builtin_amdgcn_mfma_f32_16x16x32_bf16(av, bv[nt], acc[mt][nt], 0, 0, 0);
        }
    }
}

__global__ __launch_bounds__(512, 2) void gru_kernel(
    float* __restrict__ HHf, unsigned short* __restrict__ HHbf,
    const unsigned short* __restrict__ UhT0, const unsigned short* __restrict__ UhtT0,
    const unsigned short* __restrict__ B3T,  const unsigned short* __restrict__ UhtT1,
    const unsigned short* __restrict__ WX0,
    unsigned short* __restrict__ rh0, unsigned short* __restrict__ rh1,
    float* __restrict__ z0, float* __restrict__ z1, float* __restrict__ P3,
    unsigned short* __restrict__ H2bf, const float* __restrict__ b_rzh,
    float* __restrict__ outTail, unsigned int* __restrict__ bar)
{
    __shared__ __align__(16) char smem[131072];   // 128 KB
    const int tid = threadIdx.x, lane = tid & 63, wv = tid >> 6, blk = blockIdx.x;
    const int ln = lane & 15, kg = lane >> 4;
    const float* b0 = b_rzh;
    const float* b1 = b_rzh + 1536;
    const bool oddb = (blk & 1) != 0;
    const int ngB = blk >> 1;                     // phase-B tile (S2 even / S4 odd)
    unsigned int gen = 0;

    for (int ss = 0; ss <= SEQ; ++ss){
        // ===================== phase A: S1(ss) || S3(ss-1) ==================
        // stage H [64][1024] bf16 -> LDS (pitch 2048, byte ^= (row&7)<<4)
        {
            const char* src = (const char*)HHbf;
            #pragma unroll
            for (int half = 0; half < 2; ++half){
                const int cb = tid + half*4096;
                i32x4 t0,t1,t2,t3,t4,t5,t6,t7;
                SC_LOAD8("global_load_dwordx4", t0,t1,t2,t3,t4,t5,t6,t7,
                    src + (long long)(cb       )*16, src + (long long)(cb +  512)*16,
                    src + (long long)(cb + 1024)*16, src + (long long)(cb + 1536)*16,
                    src + (long long)(cb + 2048)*16, src + (long long)(cb + 2560)*16,
                    src + (long long)(cb + 3072)*16, src + (long long)(cb + 3584)*16);
                i32x4 tt[8] = {t0,t1,t2,t3,t4,t5,t6,t7};
                #pragma unroll
                for (int j = 0; j < 8; ++j){
                    const int c = cb + j*512;
                    const int row = c >> 7;
                    *(i32x4*)(smem + ((c*16) ^ ((row & 7) << 4))) = tt[j];
                }
            }
        }
        __syncthreads();
        if (wv == 0 && ss < SEQ){
            // ---- S1: uh = h0 @ Uh0, tile ng=blk over N=1024
            const int ng = blk;
            f32x4 acc[4][4];
            mmTile<16, 2048>(UhT0 + ng*64*512, smem, ln, kg, acc);
            const int t = ss;
            #pragma unroll
            for (int mt = 0; mt < 4; ++mt){
                const int nq = ng*64 + mt*16 + kg*4;
                #pragma unroll
                for (int nt = 0; nt < 4; ++nt){
                    const int b = nt*16 + ln;
                    union { ull u; unsigned short s[4]; } wx;
                    wx.u = *(const ull*)(WX0 + (long long)(t*64 + b)*1536 + nq);
                    float sg[4];
                    #pragma unroll
                    for (int r = 0; r < 4; ++r)
                        sg[r] = sigm(acc[mt][nt][r] + bf2f(wx.s[r]) + b0[nq + r]);
                    if (nq < 512){
                        union { ull u; unsigned short s[4]; } h;
                        h.u = *(const ull*)(smem + ((b*2048 + nq*2) ^ ((b & 7) << 4)));
                        float rv[4];
                        #pragma unroll
                        for (int r = 0; r < 4; ++r) rv[r] = sg[r] * bf2f(h.s[r]);
                        sc_st8(rh0 + b*512 + nq, pack4bf(rv));
                    } else {
                        f32x4 zz = {sg[0], sg[1], sg[2], sg[3]};
                        sc_st16(z0 + b*512 + (nq - 512), zz);
                    }
                }
            }
        } else if (ss >= 1 && (wv == 1 || (wv == 2 && !oddb))){
            // ---- S3: [h0|h1] @ B3T, 24 tiles over N=1536
            const int ng = (wv == 1) ? blk : 16 + (blk >> 1);
            f32x4 acc[4][4];
            mmTile<32, 2048>(B3T + ng*64*1024, smem, ln, kg, acc);
            #pragma unroll
            for (int mt = 0; mt < 4; ++mt){
                const int nq = ng*64 + mt*16 + kg*4;
                #pragma unroll
                for (int nt = 0; nt < 4; ++nt){
                    const int b = nt*16 + ln;
                    if (nq < 512){
                        union { ull u; unsigned short s[4]; } h;
                        h.u = *(const ull*)(smem + ((b*2048 + (512 + nq)*2) ^ ((b & 7) << 4)));
                        float rv[4];
                        #pragma unroll
                        for (int r = 0; r < 4; ++r)
                            rv[r] = sigm(acc[mt][nt][r] + b1[nq + r]) * bf2f(h.s[r]);
                        sc_st8(rh1 + b*512 + nq, pack4bf(rv));
                    } else if (nq < 1024){
                        float sg[4];
                        #pragma unroll
                        for (int r = 0; r < 4; ++r)
                            sg[r] = sigm(acc[mt][nt][r] + b1[nq + r]);
                        f32x4 zz = {sg[0], sg[1], sg[2], sg[3]};
                        sc_st16(z1 + b*512 + (nq - 512), zz);
                    } else {
                        sc_st16(P3 + b*512 + (nq - 1024), acc[mt][nt]);
                    }
                }
            }
        }
        gen += NBG; gsync(bar, gen);

        // ===================== phase B: S2(ss) || S4(ss-1) ==================
        // stage rh [64][512] bf16 (pitch 1024, swizzled) + f32 column slices:
        //   Zb @ 65536, Hp @ 81920, Pp @ 98304 (odd blocks only)
        {
            const char* srcR = (const char*)(oddb ? rh1 : rh0);
            {
                i32x4 t0,t1,t2,t3,t4,t5,t6,t7;
                SC_LOAD8("global_load_dwordx4", t0,t1,t2,t3,t4,t5,t6,t7,
                    srcR + (long long)(tid       )*16, srcR + (long long)(tid +  512)*16,
                    srcR + (long long)(tid + 1024)*16, srcR + (long long)(tid + 1536)*16,
                    srcR + (long long)(tid + 2048)*16, srcR + (long long)(tid + 2560)*16,
                    srcR + (long long)(tid + 3072)*16, srcR + (long long)(tid + 3584)*16);
                i32x4 tt[8] = {t0,t1,t2,t3,t4,t5,t6,t7};
                #pragma unroll
                for (int j = 0; j < 8; ++j){
                    const int c = tid + j*512;
                    const int row = c >> 6;
                    *(i32x4*)(smem + ((c*16) ^ ((row & 7) << 4))) = tt[j];
                }
            }
            const char* srcZ = (const char*)(oddb ? z1 : z0);
            const char* srcH = (const char*)(HHf + (oddb ? 512 : 0));
            const int cb0 = ngB*64;
            {
                ull u0,u1,u2,u3,u4,u5,u6,u7;
                // c_j = tid + j*512 (j=0..3): b=c>>5, ch=c&31
                #define ZADDR(c) (srcZ + (long long)((c) >> 5)*2048 + cb0*4 + ((c) & 31)*8)
                #define HADDR(c) (srcH + (long long)((c) >> 5)*4096 + cb0*4 + ((c) & 31)*8)
                SC_LOAD8("global_load_dwordx2", u0,u1,u2,u3,u4,u5,u6,u7,
                    ZADDR(tid), ZADDR(tid+512), ZADDR(tid+1024), ZADDR(tid+1536),
                    HADDR(tid), HADDR(tid+512), HADDR(tid+1024), HADDR(tid+1536));
                #undef ZADDR
                #undef HADDR
                ull uz[4] = {u0,u1,u2,u3};
                ull uh[4] = {u4,u5,u6,u7};
                #pragma unroll
                for (int j = 0; j < 4; ++j){
                    const int c = tid + j*512;
                    const int b = c >> 5, ch = c & 31;
                    const int off = (ch*8) ^ ((b & 15) << 4);
                    *(ull*)(smem + 65536 + b*256 + off) = uz[j];
                    *(ull*)(smem + 81920 + b*256 + off) = uh[j];
                }
            }
            if (oddb){
                ull u0,u1,u2,u3;
                const char* srcP = (const char*)P3;
                #define PADDR(c) (srcP + (long long)((c) >> 5)*2048 + cb0*4 + ((c) & 31)*8)
                SC_LOAD4("global_load_dwordx2", u0,u1,u2,u3,
                    PADDR(tid), PADDR(tid+512), PADDR(tid+1024), PADDR(tid+1536));
                #undef PADDR
                ull up[4] = {u0,u1,u2,u3};
                #pragma unroll
                for (int j = 0; j < 4; ++j){
                    const int c = tid + j*512;
                    const int b = c >> 5, ch = c & 31;
                    const int off = (ch*8) ^ ((b & 15) << 4);
                    *(ull*)(smem + 98304 + b*256 + off) = up[j];
                }
            }
        }
        __syncthreads();
        if (wv == 0 && !oddb && ss < SEQ){
            // ---- S2: ht = tanh(wx_h + rh0@Uht0 + b); h0 update. tile ngB.
            f32x4 acc[4][4];
            mmTile<16, 1024>(UhtT0 + ngB*64*512, smem, ln, kg, acc);
            const int t = ss;
            #pragma unroll
            for (int mt = 0; mt < 4; ++mt){
                const int nq = ngB*64 + mt*16 + kg*4;   // < 512
                const int lc = mt*64 + kg*16;           // local col byte offset
                #pragma unroll
                for (int nt = 0; nt < 4; ++nt){
                    const int b = nt*16 + ln;
                    union { ull u; unsigned short s[4]; } wx;
                    wx.u = *(const ull*)(WX0 + (long long)(t*64 + b)*1536 + 1024 + nq);
                    const int off = lc ^ (ln << 4);
                    const float* zp = (const float*)(smem + 65536 + b*256 + off);
                    const float* hp = (const float*)(smem + 81920 + b*256 + off);
                    float hn[4];
                    #pragma unroll
                    for (int r = 0; r < 4; ++r){
                        float pre = acc[mt][nt][r] + bf2f(wx.s[r]) + b0[1024 + nq + r];
                        float ht = tanh_fast(pre);
                        float z = zp[r];
                        hn[r] = (1.0f - z)*hp[r] + z*ht;
                    }
                    f32x4 hv = {hn[0], hn[1], hn[2], hn[3]};
                    sc_st16(HHf + b*1024 + nq, hv);
                    sc_st8(HHbf + b*1024 + nq, pack4bf(hn));
                }
            }
        } else if (wv == 0 && oddb && ss >= 1){
            // ---- S4: ht = tanh(P3 + rh1@Uht1 + b); h1 update + H2bf. tile ngB.
            f32x4 acc[4][4];
            mmTile<16, 1024>(UhtT1 + ngB*64*512, smem, ln, kg, acc);
            const int t = ss - 1;
            #pragma unroll
            for (int mt = 0; mt < 4; ++mt){
                const int nq = ngB*64 + mt*16 + kg*4;   // < 512
                const int lc = mt*64 + kg*16;
                #pragma unroll
                for (int nt = 0; nt < 4; ++nt){
                    const int b = nt*16 + ln;
                    const int off = lc ^ (ln << 4);
                    const float* zp = (const float*)(smem + 65536 + b*256 + off);
                    const float* hp = (const float*)(smem + 81920 + b*256 + off);
                    const float* pp = (const float*)(smem + 98304 + b*256 + off);
                    float hn[4];
                    #pragma unroll
                    for (int r = 0; r < 4; ++r){
                        float pre = acc[mt][nt][r] + pp[r] + b1[1024 + nq + r];
                        float ht = tanh_fast(pre);
                        float z = zp[r];
                        hn[r] = (1.0f - z)*hp[r] + z*ht;
                    }
                    f32x4 hv = {hn[0], hn[1], hn[2], hn[3]};
                    sc_st16(HHf + b*1024 + 512 + nq, hv);
                    sc_st8(HHbf + b*1024 + 512 + nq, pack4bf(hn));
                    *(ull*)(H2bf + (long long)(t*64 + b)*512 + nq) = pack4bf(hn);
                }
            }
        }
        gen += NBG; gsync(bar, gen);
    }

    // h_final tail: out[(l*64+b)*512 + j] = HHf[b*1024 + l*512 + j]
    for (int c = blk*512 + tid; c < 16384; c += NBG*512){
        f32x4 v = sc_ld16(HHf + c*4);
        int b = c >> 8, cc = c & 255, l = cc >> 7, j = (cc & 127) << 2;
        *(f32x4*)(outTail + l*32768 + b*512 + j) = v;
    }
}

// ---------------------------------------------------------------- launch ----
extern "C" void kernel_launch(void* const* d_in, const int* in_sizes, int n_in,
                              void* d_out, int out_size, void* d_ws, size_t ws_size,
                              hipStream_t stream)
{
    const int*   inputs = (const int*)d_in[0];
    const float* hidden = (const float*)d_in[1];
    const float* emb    = (const float*)d_in[2];
    const float* Wx     = (const float*)d_in[3];
    const float* Uh     = (const float*)d_in[4];
    const float* Uht    = (const float*)d_in[5];
    const float* b_rzh  = (const float*)d_in[6];
    const float* dec_w  = (const float*)d_in[7];
    const float* dec_b  = (const float*)d_in[8];
    float* out = (float*)d_out;

    char* w = (char*)d_ws;
    size_t off = 0;
    auto alloc = [&](size_t bytes)->char*{
        char* p = w + off; off = (off + bytes + 255) & ~(size_t)255; return p;
    };
    unsigned short* emb_bf = (unsigned short*)alloc(4096LL*512*2);
    unsigned short* WxT0   = (unsigned short*)alloc(1536LL*512*2);
    unsigned short* WX0    = (unsigned short*)alloc(4096LL*1536*2);
    unsigned short* UhT0   = (unsigned short*)alloc(1024LL*512*2);
    unsigned short* UhtT0  = (unsigned short*)alloc(512LL*512*2);
    unsigned short* B3T    = (unsigned short*)alloc(1536LL*1024*2);
    unsigned short* UhtT1  = (unsigned short*)alloc(512LL*512*2);
    unsigned short* decpad = (unsigned short*)alloc(10112LL*512*2);
    float*          HH     = (float*)alloc(65536*4);
    unsigned short* HHbf   = (unsigned short*)alloc(65536*2);
    unsigned short* rh0    = (unsigned short*)alloc(64*512*2);
    unsigned short* rh1    = (unsigned short*)alloc(64*512*2);
    float*          z0     = (float*)alloc(64*512*4);
    float*          z1     = (float*)alloc(64*512*4);
    float*          P3     = (float*)alloc(64*512*4);
    unsigned short* H2bf   = (unsigned short*)alloc(4096LL*512*2);
    unsigned int*   bar    = (unsigned int*)alloc(256);
    if (off > ws_size) return;  // workspace too small: fail loudly via absmax

    prep_kernel<<<1024, 256, 0, stream>>>(inputs, hidden, emb, Wx, Uh, Uht, dec_w,
        emb_bf, WxT0, UhT0, UhtT0, B3T, UhtT1, decpad, HH, HHbf, bar);

    // WX0 = embed @ Wx0  (M=4096, N=1536, K=512), bf16 out
    gemm128<<<dim3(32*12), 256, 0, stream>>>(emb_bf, WxT0, 4096, 1536, 512,
        0, nullptr, WX0, nullptr, 1536);

    // persistent recurrent kernel (16 co-resident blocks, LDS-staged phases)
    gru_kernel<<<dim3(NBG), 512, 0, stream>>>(HH, HHbf, UhT0, UhtT0, B3T, UhtT1,
        WX0, rh0, rh1, z0, z1, P3, H2bf, b_rzh, out + 40960000, bar);

    // decoder: logits = H2 @ dec_w^T + dec_b  (M=4096, N=10112 padded, K=512)
    gemm128<<<dim3(32*79), 256, 0, stream>>>(H2bf, decpad, 4096, 10112, 512,
        1, out, nullptr, dec_b, 10000);
}